// Round 1
// 550.564 us; speedup vs baseline: 1.0146x; 1.0146x over previous
//
#include <hip/hip_runtime.h>
#include <cstdint>

typedef __bf16 bf16_t;
typedef __attribute__((ext_vector_type(8))) __bf16 bf16x8;
typedef __attribute__((ext_vector_type(4))) float f32x4;

#define MC_EPS 1e-8f

__device__ __forceinline__ void async_ld16(const bf16_t* g, bf16_t* l) {
  __builtin_amdgcn_global_load_lds(
      (const __attribute__((address_space(1))) void*)g,
      (__attribute__((address_space(3))) void*)l, 16, 0, 0);
}

// s[b][ci] = dot(w[b,:], affine_w[ci,:]) + affine_b[ci] + 1
__global__ void s_kernel(const float* __restrict__ w, const float* __restrict__ aw,
                         const float* __restrict__ ab, float* __restrict__ s) {
  int ci = blockIdx.x, tid = threadIdx.x;
  int b = tid >> 4, part = tid & 15;
  const float* ar = aw + (ci << 9);
  const float* wr = w + (b << 9);
  float acc = 0.f;
  for (int j = part; j < 512; j += 16) acc += wr[j] * ar[j];
  for (int off = 8; off; off >>= 1) acc += __shfl_down(acc, off, 64);
  if (part == 0) s[(b << 9) + ci] = acc + ab[ci] + 1.0f;
}

// fused: wsq[co][ci] = sum_t w^2 ; w_t[t][co][ci] = bf16(w)
__global__ void prep_w_kernel(const float* __restrict__ wgt, float* __restrict__ wsq,
                              bf16_t* __restrict__ w_t) {
  int idx = blockIdx.x * 256 + threadIdx.x;  // co*512+ci
  const float* p = wgt + (size_t)idx * 9;
  float v[9];
  float a = 0.f;
#pragma unroll
  for (int j = 0; j < 9; ++j) { v[j] = p[j]; a += v[j] * v[j]; }
  wsq[idx] = a;
#pragma unroll
  for (int j = 0; j < 9; ++j) w_t[((size_t)j << 18) + idx] = (bf16_t)v[j];
}

// d[b][co] = rsqrt(sum_ci wsq[co][ci] * s[b][ci]^2 + eps)
__global__ void d_kernel(const float* __restrict__ wsq, const float* __restrict__ s,
                         float* __restrict__ d) {
  int co = blockIdx.x, tid = threadIdx.x;
  int b = tid >> 4, part = tid & 15;
  const float* wr = wsq + (co << 9);
  const float* sr = s + (b << 9);
  float acc = 0.f;
  for (int j = part; j < 512; j += 16) { float sv = sr[j]; acc += wr[j] * sv * sv; }
  for (int off = 8; off; off >>= 1) acc += __shfl_down(acc, off, 64);
  if (part == 0) d[(b << 9) + co] = rsqrtf(acc + MC_EPS);
}

// zero only the 1-px halo border of x_pad
__global__ void halo_kernel(bf16_t* __restrict__ xp) {
  int gid = blockIdx.x * 256 + threadIdx.x;
  if (gid >= 16 * 260 * 64) return;
  int cg = gid & 63;
  int p = (gid >> 6) % 260;
  int b = (gid >> 6) / 260;
  int h, w;
  if (p < 66)       { h = 0;       w = p; }
  else if (p < 132) { h = 65;      w = p - 66; }
  else if (p < 196) { h = p - 131; w = 0; }
  else              { h = p - 195; w = 65; }
  uint4 z = {0u, 0u, 0u, 0u};
  *(uint4*)&xp[((size_t)(b * 66 + h) * 66 + w) * 512 + (cg << 3)] = z;
}

// x_pad[b][h+1][w+1][ci] = bf16(x[b][ci][h][w] * s[b][ci])  (NHWC, 1-px halo)
__global__ void xmod_kernel(const float* __restrict__ x, const float* __restrict__ s,
                            bf16_t* __restrict__ xp) {
  int b = blockIdx.x >> 6, h = blockIdx.x & 63;
  int tid = threadIdx.x;
  __shared__ __align__(16) bf16_t tile[64 * 130];
  for (int c0 = 0; c0 < 512; c0 += 128) {
    if (c0) __syncthreads();
    int w4 = (tid & 15) << 2;
    int cl = tid >> 4;
#pragma unroll
    for (int r = 0; r < 8; ++r) {
      int ci = cl + (r << 4);
      const float4 v = *(const float4*)&x[(size_t)(((b << 9) + c0 + ci) << 12) + (h << 6) + w4];
      float sv = s[(b << 9) + c0 + ci];
      tile[(w4 + 0) * 130 + ci] = (bf16_t)(v.x * sv);
      tile[(w4 + 1) * 130 + ci] = (bf16_t)(v.y * sv);
      tile[(w4 + 2) * 130 + ci] = (bf16_t)(v.z * sv);
      tile[(w4 + 3) * 130 + ci] = (bf16_t)(v.w * sv);
    }
    __syncthreads();
#pragma unroll
    for (int it = 0; it < 4; ++it) {
      int i = tid + it * 256;
      int w = i >> 4, cg = i & 15;
      const uint32_t* tp = (const uint32_t*)&tile[w * 130 + (cg << 3)];
      uint4 v = { tp[0], tp[1], tp[2], tp[3] };
      *(uint4*)&xp[((size_t)(b * 66 + h + 1) * 66 + (w + 1)) * 512 + c0 + (cg << 3)] = v;
    }
  }
}

// Implicit-GEMM conv, pipelined 8-phase-class schedule (T2+T3+T4+T5):
// 256 px x 128 co per block, 8 waves (4M x 2N, 64x64 per wave), BK=64.
// Ring-3 LDS (3 x 48 KB = 144 KB dynamic): compute tile k from slot k%3 while
// issuing global_load_lds for tile k+2 into slot (k+2)%3 = (k-1)%3 — that
// slot's reads finished at the previous tile boundary, so stage-issue is
// race-free without draining. Counted s_waitcnt vmcnt(6) at tile boundaries
// (never 0 until the last 2 tiles); raw s_barrier (no compiler vmcnt(0) drain).
// 2 phases/tile: {8 ds_read_b128 + 3 stage issues -> barrier -> setprio(1) ->
// 16 MFMA -> setprio(0) -> barrier}. XOR swizzle: source ci-group ^= row&7,
// read phys = ((s<<2)|quad) ^ (lr&7) — 0 bank conflicts (verified layout).
// XCD swizzle: g&7 -> 32-mb slab per XCD, 4 nb-siblings co-resident for L2 A-reuse.
__global__ __launch_bounds__(512, 1) void conv_kernel(
    const bf16_t* __restrict__ xp, const bf16_t* __restrict__ w_t,
    const float* __restrict__ d, float* __restrict__ out) {
  extern __shared__ bf16_t smem[];   // 3 slots x (A[256][64]=16384 el | B[128][64]=8192 el)
  const int tid = threadIdx.x, lane = tid & 63;
  const int g = blockIdx.x;
  const int xcd = g & 7;
  const int slot = g >> 3;                  // 0..127
  const int mb = (xcd << 5) + (slot >> 2);  // 0..255
  const int nb = slot & 3;
  const int b = mb >> 4;
  const int h0 = (mb & 15) << 2;            // 4 output rows per block
  const int n0 = nb << 7;                   // 128 co per block
  const int wv = tid >> 6, wm = wv >> 1, wn = wv & 1;
  const int quad = lane >> 4, lr = lane & 15;

  // per-thread staging invariants (A: 4 loads/tile, B: 2 loads/tile)
  size_t a_src[4]; int a_dst[4];
#pragma unroll
  for (int j = 0; j < 4; ++j) {
    int e = (j << 9) + tid;                  // [0,2048)
    int p = e >> 3;                          // pixel [0,256)
    int kk = ((e & 7) ^ (p & 7)) << 3;       // swizzled logical ci-group
    a_src[j] = ((size_t)((b * 66 + h0 + (p >> 6)) * 66 + (p & 63)) << 9) + kk;
    a_dst[j] = (e & ~63) << 3;               // wave-uniform linear dest
  }
  size_t b_src[2]; int b_dst[2];
#pragma unroll
  for (int j = 0; j < 2; ++j) {
    int e = (j << 9) + tid;                  // [0,1024)
    int n = e >> 3;                          // co row [0,128)
    int kk = ((e & 7) ^ (n & 7)) << 3;
    b_src[j] = ((size_t)(n0 + n) << 9) + kk;
    b_dst[j] = 16384 + ((e & ~63) << 3);
  }

  f32x4 acc[4][4];
#pragma unroll
  for (int i = 0; i < 4; ++i)
#pragma unroll
    for (int j = 0; j < 4; ++j) acc[i][j] = (f32x4){0.f, 0.f, 0.f, 0.f};

  // prologue: stage tile 0 (tap0, ci0=0) -> slot 0, tile 1 (tap0, ci0=64) -> slot 1
#pragma unroll
  for (int j = 0; j < 4; ++j) async_ld16(xp + a_src[j], &smem[a_dst[j]]);
#pragma unroll
  for (int j = 0; j < 2; ++j) async_ld16(w_t + b_src[j], &smem[b_dst[j]]);
#pragma unroll
  for (int j = 0; j < 4; ++j) async_ld16(xp + a_src[j] + 64, &smem[24576 + a_dst[j]]);
#pragma unroll
  for (int j = 0; j < 2; ++j) async_ld16(w_t + b_src[j] + 64, &smem[24576 + b_dst[j]]);
  asm volatile("s_waitcnt vmcnt(6)" ::: "memory");   // tile 0 landed; tile 1 in flight
  __builtin_amdgcn_s_barrier();

  int rs = 0;  // ring slot of tile k
  for (int k = 0; k < 72; ++k) {
    const int abase = rs * 24576;
    const int bbase = abase + 16384;
    const int kp = k + 2;                     // prefetch tile
    const int rp = (rs == 0) ? 2 : rs - 1;    // (k+2)%3
    const int pbase = rp * 24576;
    const int tp = kp >> 3;
    const int khp = tp / 3, kwp = tp - khp * 3;
    const size_t a_off = ((size_t)(khp * 66 + kwp) << 9) + ((kp & 7) << 6);
    const size_t b_off = ((size_t)tp << 18) + ((kp & 7) << 6);
    const bool pf = kp < 72;

    bf16x8 af[4], bfr[4];
    // ---------------- phase 0 (K-half s=0) ----------------
#pragma unroll
    for (int mt = 0; mt < 4; ++mt)
      af[mt] = *(const bf16x8*)&smem[abase + (((wm << 6) + (mt << 4) + lr) << 6) +
                                     ((quad ^ (lr & 7)) << 3)];
#pragma unroll
    for (int nt = 0; nt < 4; ++nt)
      bfr[nt] = *(const bf16x8*)&smem[bbase + (((wn << 6) + (nt << 4) + lr) << 6) +
                                      ((quad ^ (lr & 7)) << 3)];
    if (pf) {
      async_ld16(xp + a_src[0] + a_off, &smem[pbase + a_dst[0]]);
      async_ld16(xp + a_src[1] + a_off, &smem[pbase + a_dst[1]]);
      async_ld16(xp + a_src[2] + a_off, &smem[pbase + a_dst[2]]);
    }
    __builtin_amdgcn_s_barrier();
    __builtin_amdgcn_s_setprio(1);
#pragma unroll
    for (int mt = 0; mt < 4; ++mt)
#pragma unroll
      for (int nt = 0; nt < 4; ++nt)
        acc[mt][nt] = __builtin_amdgcn_mfma_f32_16x16x32_bf16(af[mt], bfr[nt], acc[mt][nt], 0, 0, 0);
    __builtin_amdgcn_s_setprio(0);
    __builtin_amdgcn_s_barrier();
    // ---------------- phase 1 (K-half s=1) ----------------
#pragma unroll
    for (int mt = 0; mt < 4; ++mt)
      af[mt] = *(const bf16x8*)&smem[abase + (((wm << 6) + (mt << 4) + lr) << 6) +
                                     (((4 | quad) ^ (lr & 7)) << 3)];
#pragma unroll
    for (int nt = 0; nt < 4; ++nt)
      bfr[nt] = *(const bf16x8*)&smem[bbase + (((wn << 6) + (nt << 4) + lr) << 6) +
                                      (((4 | quad) ^ (lr & 7)) << 3)];
    if (pf) {
      async_ld16(xp + a_src[3] + a_off, &smem[pbase + a_dst[3]]);
      async_ld16(w_t + b_src[0] + b_off, &smem[pbase + b_dst[0]]);
      async_ld16(w_t + b_src[1] + b_off, &smem[pbase + b_dst[1]]);
    }
    __builtin_amdgcn_s_barrier();
    __builtin_amdgcn_s_setprio(1);
#pragma unroll
    for (int mt = 0; mt < 4; ++mt)
#pragma unroll
      for (int nt = 0; nt < 4; ++nt)
        acc[mt][nt] = __builtin_amdgcn_mfma_f32_16x16x32_bf16(af[mt], bfr[nt], acc[mt][nt], 0, 0, 0);
    __builtin_amdgcn_s_setprio(0);
    // tile boundary: wait until tile k+1 fully landed; keep tile k+2's 6 loads in flight
    if (k < 70) asm volatile("s_waitcnt vmcnt(6)" ::: "memory");
    else        asm volatile("s_waitcnt vmcnt(0)" ::: "memory");
    __builtin_amdgcn_s_barrier();
    rs = (rs == 2) ? 0 : rs + 1;
  }

  // epilogue: out[b][co][h][w] = acc * d[b][co]
#pragma unroll
  for (int nt = 0; nt < 4; ++nt) {
    const int n = n0 + (wn << 6) + (nt << 4) + lr;
    const float dv = d[(b << 9) + n];
#pragma unroll
    for (int mt = 0; mt < 4; ++mt) {
#pragma unroll
      for (int r = 0; r < 4; ++r) {
        int m = (wm << 6) + (mt << 4) + (quad << 2) + r;   // pixel in tile [0,256)
        int h = h0 + (m >> 6), w = m & 63;
        out[((size_t)((b << 9) + n) << 12) + (h << 6) + w] = acc[mt][nt][r] * dv;
      }
    }
  }
}

extern "C" void kernel_launch(void* const* d_in, const int* in_sizes, int n_in,
                              void* d_out, int out_size, void* d_ws, size_t ws_size,
                              hipStream_t stream) {
  const float* x      = (const float*)d_in[0];   // [16,512,64,64]
  const float* w      = (const float*)d_in[1];   // [16,512]
  const float* weight = (const float*)d_in[2];   // [512,512,3,3]
  const float* aw     = (const float*)d_in[3];   // [512,512]
  const float* ab     = (const float*)d_in[4];   // [512]
  float* out = (float*)d_out;

  char* ws = (char*)d_ws;
  const size_t XP_BYTES  = (size_t)16 * 66 * 66 * 512 * 2;  // 71,368,704
  const size_t WT_BYTES  = (size_t)9 * 512 * 512 * 2;       //  4,718,592
  bf16_t* xp   = (bf16_t*)ws;
  bf16_t* w_t  = (bf16_t*)(ws + XP_BYTES);
  float*  s    = (float*)(ws + XP_BYTES + WT_BYTES);
  float*  wsq  = (float*)(ws + XP_BYTES + WT_BYTES + 32768);
  float*  dbuf = (float*)(ws + XP_BYTES + WT_BYTES + 32768 + 1048576);

  static int attr_done = 0;
  if (!attr_done) {
    hipFuncSetAttribute(reinterpret_cast<const void*>(conv_kernel),
                        hipFuncAttributeMaxDynamicSharedMemorySize, 147456);
    attr_done = 1;
  }

  halo_kernel<<<1040, 256, 0, stream>>>(xp);
  s_kernel<<<512, 256, 0, stream>>>(w, aw, ab, s);
  prep_w_kernel<<<1024, 256, 0, stream>>>(weight, wsq, w_t);
  d_kernel<<<512, 256, 0, stream>>>(wsq, s, dbuf);
  xmod_kernel<<<1024, 256, 0, stream>>>(x, s, xp);
  conv_kernel<<<1024, 512, 147456, stream>>>(xp, w_t, dbuf, out);
}

// Round 2
// 525.695 us; speedup vs baseline: 1.0626x; 1.0473x over previous
//
#include <hip/hip_runtime.h>
#include <cstdint>

typedef __bf16 bf16_t;
typedef __attribute__((ext_vector_type(8))) __bf16 bf16x8;
typedef __attribute__((ext_vector_type(4))) float f32x4;

#define MC_EPS 1e-8f

__device__ __forceinline__ void async_ld16(const bf16_t* g, bf16_t* l) {
  __builtin_amdgcn_global_load_lds(
      (const __attribute__((address_space(1))) void*)g,
      (__attribute__((address_space(3))) void*)l, 16, 0, 0);
}

// s[b][ci] = dot(w[b,:], affine_w[ci,:]) + affine_b[ci] + 1
__global__ void s_kernel(const float* __restrict__ w, const float* __restrict__ aw,
                         const float* __restrict__ ab, float* __restrict__ s) {
  int ci = blockIdx.x, tid = threadIdx.x;
  int b = tid >> 4, part = tid & 15;
  const float* ar = aw + (ci << 9);
  const float* wr = w + (b << 9);
  float acc = 0.f;
  for (int j = part; j < 512; j += 16) acc += wr[j] * ar[j];
  for (int off = 8; off; off >>= 1) acc += __shfl_down(acc, off, 64);
  if (part == 0) s[(b << 9) + ci] = acc + ab[ci] + 1.0f;
}

// fused: wsq[co][ci] = sum_t w^2 ; w_t[t][co][ci] = bf16(w)
__global__ void prep_w_kernel(const float* __restrict__ wgt, float* __restrict__ wsq,
                              bf16_t* __restrict__ w_t) {
  int idx = blockIdx.x * 256 + threadIdx.x;  // co*512+ci
  const float* p = wgt + (size_t)idx * 9;
  float v[9];
  float a = 0.f;
#pragma unroll
  for (int j = 0; j < 9; ++j) { v[j] = p[j]; a += v[j] * v[j]; }
  wsq[idx] = a;
#pragma unroll
  for (int j = 0; j < 9; ++j) w_t[((size_t)j << 18) + idx] = (bf16_t)v[j];
}

// d[b][co] = rsqrt(sum_ci wsq[co][ci] * s[b][ci]^2 + eps)
__global__ void d_kernel(const float* __restrict__ wsq, const float* __restrict__ s,
                         float* __restrict__ d) {
  int co = blockIdx.x, tid = threadIdx.x;
  int b = tid >> 4, part = tid & 15;
  const float* wr = wsq + (co << 9);
  const float* sr = s + (b << 9);
  float acc = 0.f;
  for (int j = part; j < 512; j += 16) { float sv = sr[j]; acc += wr[j] * sv * sv; }
  for (int off = 8; off; off >>= 1) acc += __shfl_down(acc, off, 64);
  if (part == 0) d[(b << 9) + co] = rsqrtf(acc + MC_EPS);
}

// zero only the 1-px halo border of x_pad
__global__ void halo_kernel(bf16_t* __restrict__ xp) {
  int gid = blockIdx.x * 256 + threadIdx.x;
  if (gid >= 16 * 260 * 64) return;
  int cg = gid & 63;
  int p = (gid >> 6) % 260;
  int b = (gid >> 6) / 260;
  int h, w;
  if (p < 66)       { h = 0;       w = p; }
  else if (p < 132) { h = 65;      w = p - 66; }
  else if (p < 196) { h = p - 131; w = 0; }
  else              { h = p - 195; w = 65; }
  uint4 z = {0u, 0u, 0u, 0u};
  *(uint4*)&xp[((size_t)(b * 66 + h) * 66 + w) * 512 + (cg << 3)] = z;
}

// x_pad[b][h+1][w+1][ci] = bf16(x[b][ci][h][w] * s[b][ci])  (NHWC, 1-px halo)
__global__ void xmod_kernel(const float* __restrict__ x, const float* __restrict__ s,
                            bf16_t* __restrict__ xp) {
  int b = blockIdx.x >> 6, h = blockIdx.x & 63;
  int tid = threadIdx.x;
  __shared__ __align__(16) bf16_t tile[64 * 130];
  for (int c0 = 0; c0 < 512; c0 += 128) {
    if (c0) __syncthreads();
    int w4 = (tid & 15) << 2;
    int cl = tid >> 4;
#pragma unroll
    for (int r = 0; r < 8; ++r) {
      int ci = cl + (r << 4);
      const float4 v = *(const float4*)&x[(size_t)(((b << 9) + c0 + ci) << 12) + (h << 6) + w4];
      float sv = s[(b << 9) + c0 + ci];
      tile[(w4 + 0) * 130 + ci] = (bf16_t)(v.x * sv);
      tile[(w4 + 1) * 130 + ci] = (bf16_t)(v.y * sv);
      tile[(w4 + 2) * 130 + ci] = (bf16_t)(v.z * sv);
      tile[(w4 + 3) * 130 + ci] = (bf16_t)(v.w * sv);
    }
    __syncthreads();
#pragma unroll
    for (int it = 0; it < 4; ++it) {
      int i = tid + it * 256;
      int w = i >> 4, cg = i & 15;
      const uint32_t* tp = (const uint32_t*)&tile[w * 130 + (cg << 3)];
      uint4 v = { tp[0], tp[1], tp[2], tp[3] };
      *(uint4*)&xp[((size_t)(b * 66 + h + 1) * 66 + (w + 1)) * 512 + c0 + (cg << 3)] = v;
    }
  }
}

// Implicit-GEMM conv. Key ratios: per-wave 128x64 output (8 waves = 2M x 4N over
// BM=256 px x BN=256 co) -> 12 ds_read_b128 per 32 MFMA (0.375 reads/MFMA) so
// LDS-read BW (~85-128 B/cyc/CU) no longer caps MfmaUtil below ~90%.
// BK=32; slot = A[256][32]+B[256][32] = 32 KB; ring-4 (128 KB), prefetch depth 3.
// ONE barrier + ONE counted vmcnt(8) per K-tile (never drains in main loop);
// reads+MFMAs live in a single barrier-free region so the compiler interleaves
// ds_read issue into MFMA pipe gaps (the mechanism that gave the 50% baseline).
// 64B-row swizzle: phys ci-group = logical ^ ((row>>1)&3) -> every 16B slot read
// exactly once per wave-access = balanced banks (2-way only, free per m136).
// XCD swizzle: g&7 -> 32-mb slab/XCD, nb pair adjacent (w_t 4.5MB L2-resident).
__global__ __launch_bounds__(512, 2) void conv_kernel(
    const bf16_t* __restrict__ xp, const bf16_t* __restrict__ w_t,
    const float* __restrict__ d, float* __restrict__ out) {
  extern __shared__ bf16_t smem[];   // 4 slots x 16384 elems (A 8192 | B 8192) = 128 KB
  const int tid = threadIdx.x, lane = tid & 63;
  const int g = blockIdx.x;
  const int xcd = g & 7;
  const int slot = g >> 3;                  // 0..63
  const int mb = (xcd << 5) + (slot >> 1);  // 0..255
  const int nb = slot & 1;
  const int b = mb >> 4;
  const int h0 = (mb & 15) << 2;            // 4 output rows per block
  const int n0 = nb << 8;                   // 256 co per block
  const int wv = tid >> 6;
  const int wm = wv >> 2, wn = wv & 3;      // 2M x 4N, per-wave 128 px x 64 co
  const int quad = lane >> 4, lr = lane & 15;

  // per-thread staging invariants (2 A-loads + 2 B-loads per K-tile)
  int a_base[2], a_dst[2], b_base[2], b_dst[2];
#pragma unroll
  for (int j = 0; j < 2; ++j) {
    int e = (j << 9) + tid;                 // [0,1024)
    int p = e >> 2;                         // px / co row [0,256)
    int cig = (e & 3) ^ ((p >> 1) & 3);     // swizzled logical ci-group (8 elems)
    a_base[j] = ((b * 66 + h0 + (p >> 6)) * 66 + (p & 63)) * 512 + (cig << 3);
    a_dst[j] = (e & ~63) << 3;              // wave-uniform linear dest
    b_base[j] = ((n0 + p) << 9) + (cig << 3);
    b_dst[j] = 8192 + a_dst[j];
  }

  f32x4 acc[8][4];
#pragma unroll
  for (int i = 0; i < 8; ++i)
#pragma unroll
    for (int j = 0; j < 4; ++j) acc[i][j] = (f32x4){0.f, 0.f, 0.f, 0.f};

  // prologue: stage tiles 0..2 (tap 0, ci0 = kt*32) into slots 0..2
#pragma unroll
  for (int kt = 0; kt < 3; ++kt) {
    const int cio = kt << 5;
    const int sb = kt << 14;
    async_ld16(xp + a_base[0] + cio, &smem[sb + a_dst[0]]);
    async_ld16(xp + a_base[1] + cio, &smem[sb + a_dst[1]]);
    async_ld16(w_t + b_base[0] + cio, &smem[sb + b_dst[0]]);
    async_ld16(w_t + b_base[1] + cio, &smem[sb + b_dst[1]]);
  }
  asm volatile("s_waitcnt vmcnt(8)" ::: "memory");   // tile 0 landed; 1,2 in flight
  __builtin_amdgcn_s_barrier();

  const int arow = (wm << 7) + lr;
  const int brow = (wn << 6) + lr;
  const int phys = (quad ^ ((lr >> 1) & 3)) << 3;

  for (int k = 0; k < 144; ++k) {            // 9 taps x 16 ci-tiles of 32
    const int sb = (k & 3) << 14;
    const int kp = k + 3;
    const int pb = (kp & 3) << 14;
    const bool pf = kp < 144;
    int aoff = 0, boff = 0;
    if (pf) {
      const int tp = kp >> 4;
      const int khp = tp / 3, kwp = tp - khp * 3;
      aoff = ((khp * 66 + kwp) << 9) + ((kp & 15) << 5);
      boff = (tp << 18) + ((kp & 15) << 5);
    }

    bf16x8 af0[4], af1[4], bfr[4];
#pragma unroll
    for (int nt = 0; nt < 4; ++nt)
      bfr[nt] = *(const bf16x8*)&smem[sb + 8192 + ((brow + (nt << 4)) << 5) + phys];
#pragma unroll
    for (int mt = 0; mt < 4; ++mt)
      af0[mt] = *(const bf16x8*)&smem[sb + ((arow + (mt << 4)) << 5) + phys];
#pragma unroll
    for (int mt = 0; mt < 4; ++mt)
      af1[mt] = *(const bf16x8*)&smem[sb + ((arow + 64 + (mt << 4)) << 5) + phys];
    if (pf) {
      async_ld16(xp + a_base[0] + aoff, &smem[pb + a_dst[0]]);
      async_ld16(xp + a_base[1] + aoff, &smem[pb + a_dst[1]]);
    }
#pragma unroll
    for (int mt = 0; mt < 4; ++mt)
#pragma unroll
      for (int nt = 0; nt < 4; ++nt)
        acc[mt][nt] = __builtin_amdgcn_mfma_f32_16x16x32_bf16(af0[mt], bfr[nt], acc[mt][nt], 0, 0, 0);
    if (pf) {
      async_ld16(w_t + b_base[0] + boff, &smem[pb + b_dst[0]]);
      async_ld16(w_t + b_base[1] + boff, &smem[pb + b_dst[1]]);
    }
#pragma unroll
    for (int mt = 0; mt < 4; ++mt)
#pragma unroll
      for (int nt = 0; nt < 4; ++nt)
        acc[4 + mt][nt] = __builtin_amdgcn_mfma_f32_16x16x32_bf16(af1[mt], bfr[nt], acc[4 + mt][nt], 0, 0, 0);

    // tile boundary: tile k+1 must be landed; keep k+2,k+3 (8 loads) in flight
    if (k < 141)      asm volatile("s_waitcnt vmcnt(8)" ::: "memory");
    else if (k == 141) asm volatile("s_waitcnt vmcnt(4)" ::: "memory");
    else              asm volatile("s_waitcnt vmcnt(0)" ::: "memory");
    __builtin_amdgcn_s_barrier();
  }

  // epilogue: out[b][co][h][w] = acc * d[b][co]
#pragma unroll
  for (int nt = 0; nt < 4; ++nt) {
    const int n = n0 + (wn << 6) + (nt << 4) + lr;
    const float dv = d[(b << 9) + n];
#pragma unroll
    for (int mt = 0; mt < 8; ++mt) {
#pragma unroll
      for (int r = 0; r < 4; ++r) {
        int m = (wm << 7) + (mt << 4) + (quad << 2) + r;   // pixel in tile [0,256)
        int h = h0 + (m >> 6), w = m & 63;
        out[((size_t)((b << 9) + n) << 12) + (h << 6) + w] = acc[mt][nt][r] * dv;
      }
    }
  }
}

extern "C" void kernel_launch(void* const* d_in, const int* in_sizes, int n_in,
                              void* d_out, int out_size, void* d_ws, size_t ws_size,
                              hipStream_t stream) {
  const float* x      = (const float*)d_in[0];   // [16,512,64,64]
  const float* w      = (const float*)d_in[1];   // [16,512]
  const float* weight = (const float*)d_in[2];   // [512,512,3,3]
  const float* aw     = (const float*)d_in[3];   // [512,512]
  const float* ab     = (const float*)d_in[4];   // [512]
  float* out = (float*)d_out;

  char* ws = (char*)d_ws;
  const size_t XP_BYTES  = (size_t)16 * 66 * 66 * 512 * 2;  // 71,368,704
  const size_t WT_BYTES  = (size_t)9 * 512 * 512 * 2;       //  4,718,592
  bf16_t* xp   = (bf16_t*)ws;
  bf16_t* w_t  = (bf16_t*)(ws + XP_BYTES);
  float*  s    = (float*)(ws + XP_BYTES + WT_BYTES);
  float*  wsq  = (float*)(ws + XP_BYTES + WT_BYTES + 32768);
  float*  dbuf = (float*)(ws + XP_BYTES + WT_BYTES + 32768 + 1048576);

  static int attr_done = 0;
  if (!attr_done) {
    hipFuncSetAttribute(reinterpret_cast<const void*>(conv_kernel),
                        hipFuncAttributeMaxDynamicSharedMemorySize, 131072);
    attr_done = 1;
  }

  halo_kernel<<<1040, 256, 0, stream>>>(xp);
  s_kernel<<<512, 256, 0, stream>>>(w, aw, ab, s);
  prep_w_kernel<<<1024, 256, 0, stream>>>(weight, wsq, w_t);
  d_kernel<<<512, 256, 0, stream>>>(wsq, s, dbuf);
  xmod_kernel<<<1024, 256, 0, stream>>>(x, s, xp);
  conv_kernel<<<512, 512, 131072, stream>>>(xp, w_t, dbuf, out);
}

// Round 3
// 507.329 us; speedup vs baseline: 1.1011x; 1.0362x over previous
//
#include <hip/hip_runtime.h>
#include <cstdint>

typedef __bf16 bf16_t;
typedef __attribute__((ext_vector_type(8))) __bf16 bf16x8;
typedef __attribute__((ext_vector_type(4))) float f32x4;

#define MC_EPS 1e-8f

__device__ __forceinline__ void async_ld16(const bf16_t* g, bf16_t* l) {
  __builtin_amdgcn_global_load_lds(
      (const __attribute__((address_space(1))) void*)g,
      (__attribute__((address_space(3))) void*)l, 16, 0, 0);
}

// s[b][ci] = dot(w[b,:], affine_w[ci,:]) + affine_b[ci] + 1
__global__ void s_kernel(const float* __restrict__ w, const float* __restrict__ aw,
                         const float* __restrict__ ab, float* __restrict__ s) {
  int ci = blockIdx.x, tid = threadIdx.x;
  int b = tid >> 4, part = tid & 15;
  const float* ar = aw + (ci << 9);
  const float* wr = w + (b << 9);
  float acc = 0.f;
  for (int j = part; j < 512; j += 16) acc += wr[j] * ar[j];
  for (int off = 8; off; off >>= 1) acc += __shfl_down(acc, off, 64);
  if (part == 0) s[(b << 9) + ci] = acc + ab[ci] + 1.0f;
}

// fused: wsq[co][ci] = sum_t w^2 ; w_t[t][co][ci] = bf16(w)
__global__ void prep_w_kernel(const float* __restrict__ wgt, float* __restrict__ wsq,
                              bf16_t* __restrict__ w_t) {
  int idx = blockIdx.x * 256 + threadIdx.x;  // co*512+ci
  const float* p = wgt + (size_t)idx * 9;
  float v[9];
  float a = 0.f;
#pragma unroll
  for (int j = 0; j < 9; ++j) { v[j] = p[j]; a += v[j] * v[j]; }
  wsq[idx] = a;
#pragma unroll
  for (int j = 0; j < 9; ++j) w_t[((size_t)j << 18) + idx] = (bf16_t)v[j];
}

// d[b][co] = rsqrt(sum_ci wsq[co][ci] * s[b][ci]^2 + eps)
__global__ void d_kernel(const float* __restrict__ wsq, const float* __restrict__ s,
                         float* __restrict__ d) {
  int co = blockIdx.x, tid = threadIdx.x;
  int b = tid >> 4, part = tid & 15;
  const float* wr = wsq + (co << 9);
  const float* sr = s + (b << 9);
  float acc = 0.f;
  for (int j = part; j < 512; j += 16) { float sv = sr[j]; acc += wr[j] * sv * sv; }
  for (int off = 8; off; off >>= 1) acc += __shfl_down(acc, off, 64);
  if (part == 0) d[(b << 9) + co] = rsqrtf(acc + MC_EPS);
}

// zero only the 1-px halo border of x_pad
__global__ void halo_kernel(bf16_t* __restrict__ xp) {
  int gid = blockIdx.x * 256 + threadIdx.x;
  if (gid >= 16 * 260 * 64) return;
  int cg = gid & 63;
  int p = (gid >> 6) % 260;
  int b = (gid >> 6) / 260;
  int h, w;
  if (p < 66)       { h = 0;       w = p; }
  else if (p < 132) { h = 65;      w = p - 66; }
  else if (p < 196) { h = p - 131; w = 0; }
  else              { h = p - 195; w = 65; }
  uint4 z = {0u, 0u, 0u, 0u};
  *(uint4*)&xp[((size_t)(b * 66 + h) * 66 + w) * 512 + (cg << 3)] = z;
}

// x_pad[b][h+1][w+1][ci] = bf16(x[b][ci][h][w] * s[b][ci])  (NHWC, 1-px halo)
__global__ void xmod_kernel(const float* __restrict__ x, const float* __restrict__ s,
                            bf16_t* __restrict__ xp) {
  int b = blockIdx.x >> 6, h = blockIdx.x & 63;
  int tid = threadIdx.x;
  __shared__ __align__(16) bf16_t tile[64 * 130];
  for (int c0 = 0; c0 < 512; c0 += 128) {
    if (c0) __syncthreads();
    int w4 = (tid & 15) << 2;
    int cl = tid >> 4;
#pragma unroll
    for (int r = 0; r < 8; ++r) {
      int ci = cl + (r << 4);
      const float4 v = *(const float4*)&x[(size_t)(((b << 9) + c0 + ci) << 12) + (h << 6) + w4];
      float sv = s[(b << 9) + c0 + ci];
      tile[(w4 + 0) * 130 + ci] = (bf16_t)(v.x * sv);
      tile[(w4 + 1) * 130 + ci] = (bf16_t)(v.y * sv);
      tile[(w4 + 2) * 130 + ci] = (bf16_t)(v.z * sv);
      tile[(w4 + 3) * 130 + ci] = (bf16_t)(v.w * sv);
    }
    __syncthreads();
#pragma unroll
    for (int it = 0; it < 4; ++it) {
      int i = tid + it * 256;
      int w = i >> 4, cg = i & 15;
      const uint32_t* tp = (const uint32_t*)&tile[w * 130 + (cg << 3)];
      uint4 v = { tp[0], tp[1], tp[2], tp[3] };
      *(uint4*)&xp[((size_t)(b * 66 + h + 1) * 66 + (w + 1)) * 512 + c0 + (cg << 3)] = v;
    }
  }
}

// Implicit-GEMM conv with REGISTER DOUBLE-BUFFERING across the tile barrier.
// BM=256 px x BN=256 co, 8 waves (2M x 4N, 128x64 per wave), BK=32, ring-4 LDS
// (128 KB). Invariant entering tile k: fragments of k are in registers (read
// during k-1) AND slot (k+1)%4 has landed. Tile k's stream: issue 12 ds_reads
// for tile k+1 -> other reg set; issue 4 global_load_lds for tile k+3 into slot
// (k+3)%4=(k-1)%4 (whose reads drained before the previous barrier); 32 MFMAs
// on current set (compiler interleaves the issues into MFMA shadow, lgkmcnt(12)
// loop-carried dep). Boundary: vmcnt(4) = tile k+2 landed (k+3 stays in
// flight, never drains), one s_barrier. This overlaps the ~1130cy LDS-read
// window with the ~1240cy MFMA window that round-2's lockstep serialized.
// Swizzle (verified, 0 conflicts): stage cig = (e&3)^((p>>1)&3), read phys =
// (quad^((lr>>1)&3))<<3. XCD swizzle: g&7 -> 32-mb slab/XCD.
#define RDFRAG(SB, F)                                                           \
  { const int sbb_ = (SB);                                                      \
    _Pragma("unroll") for (int nt = 0; nt < 4; ++nt)                            \
      F[8 + nt] = *(const bf16x8*)&smem[sbb_ + 8192 + ((brow + (nt << 4)) << 5) + phys]; \
    _Pragma("unroll") for (int mt = 0; mt < 4; ++mt)                            \
      F[mt] = *(const bf16x8*)&smem[sbb_ + ((arow + (mt << 4)) << 5) + phys];   \
    _Pragma("unroll") for (int mt = 0; mt < 4; ++mt)                            \
      F[4 + mt] = *(const bf16x8*)&smem[sbb_ + ((arow + 64 + (mt << 4)) << 5) + phys]; }

#define TILE_STEP(K, FR, FW)                                                    \
  { const int k_ = (K);                                                         \
    if (k_ + 1 < 144) { RDFRAG(((k_ + 1) & 3) << 14, FW) }                      \
    if (k_ + 3 < 144) {                                                         \
      const int kp_ = k_ + 3;                                                   \
      const int pb_ = (kp_ & 3) << 14;                                          \
      const int tp_ = kp_ >> 4;                                                 \
      const int kh_ = tp_ / 3, kw_ = tp_ - kh_ * 3;                             \
      const int ao_ = ((kh_ * 66 + kw_) << 9) + ((kp_ & 15) << 5);              \
      const int bo_ = (tp_ << 18) + ((kp_ & 15) << 5);                          \
      async_ld16(xp + a_base[0] + ao_, &smem[pb_ + a_dst[0]]);                  \
      async_ld16(xp + a_base[1] + ao_, &smem[pb_ + a_dst[1]]);                  \
      async_ld16(w_t + b_base[0] + bo_, &smem[pb_ + b_dst[0]]);                 \
      async_ld16(w_t + b_base[1] + bo_, &smem[pb_ + b_dst[1]]);                 \
    }                                                                           \
    _Pragma("unroll") for (int mt = 0; mt < 4; ++mt)                            \
      _Pragma("unroll") for (int nt = 0; nt < 4; ++nt)                          \
        acc[mt][nt] = __builtin_amdgcn_mfma_f32_16x16x32_bf16(FR[mt], FR[8 + nt], acc[mt][nt], 0, 0, 0); \
    _Pragma("unroll") for (int mt = 0; mt < 4; ++mt)                            \
      _Pragma("unroll") for (int nt = 0; nt < 4; ++nt)                          \
        acc[4 + mt][nt] = __builtin_amdgcn_mfma_f32_16x16x32_bf16(FR[4 + mt], FR[8 + nt], acc[4 + mt][nt], 0, 0, 0); \
    if (k_ < 141) asm volatile("s_waitcnt vmcnt(4)" ::: "memory");              \
    else          asm volatile("s_waitcnt vmcnt(0)" ::: "memory");              \
    if (k_ < 143) __builtin_amdgcn_s_barrier(); }

__global__ __launch_bounds__(512, 2) void conv_kernel(
    const bf16_t* __restrict__ xp, const bf16_t* __restrict__ w_t,
    const float* __restrict__ d, float* __restrict__ out) {
  extern __shared__ bf16_t smem[];   // 4 slots x 16384 elems (A 8192 | B 8192) = 128 KB
  const int tid = threadIdx.x, lane = tid & 63;
  const int g = blockIdx.x;
  const int xcd = g & 7;
  const int slot = g >> 3;                  // 0..63
  const int mb = (xcd << 5) + (slot >> 1);  // 0..255
  const int nb = slot & 1;
  const int b = mb >> 4;
  const int h0 = (mb & 15) << 2;            // 4 output rows per block
  const int n0 = nb << 8;                   // 256 co per block
  const int wv = tid >> 6;
  const int wm = wv >> 2, wn = wv & 3;      // 2M x 4N, per-wave 128 px x 64 co
  const int quad = lane >> 4, lr = lane & 15;

  // per-thread staging invariants (2 A-loads + 2 B-loads per K-tile)
  int a_base[2], a_dst[2], b_base[2], b_dst[2];
#pragma unroll
  for (int j = 0; j < 2; ++j) {
    int e = (j << 9) + tid;                 // [0,1024)
    int p = e >> 2;                         // px / co row [0,256)
    int cig = (e & 3) ^ ((p >> 1) & 3);     // swizzled logical ci-group (8 elems)
    a_base[j] = ((b * 66 + h0 + (p >> 6)) * 66 + (p & 63)) * 512 + (cig << 3);
    a_dst[j] = (e & ~63) << 3;              // wave-uniform linear dest
    b_base[j] = ((n0 + p) << 9) + (cig << 3);
    b_dst[j] = 8192 + a_dst[j];
  }

  f32x4 acc[8][4];
#pragma unroll
  for (int i = 0; i < 8; ++i)
#pragma unroll
    for (int j = 0; j < 4; ++j) acc[i][j] = (f32x4){0.f, 0.f, 0.f, 0.f};

  // prologue: stage tiles 0..2 (tap 0, ci0 = kt*32) into slots 0..2
#pragma unroll
  for (int kt = 0; kt < 3; ++kt) {
    const int cio = kt << 5;
    const int sb = kt << 14;
    async_ld16(xp + a_base[0] + cio, &smem[sb + a_dst[0]]);
    async_ld16(xp + a_base[1] + cio, &smem[sb + a_dst[1]]);
    async_ld16(w_t + b_base[0] + cio, &smem[sb + b_dst[0]]);
    async_ld16(w_t + b_base[1] + cio, &smem[sb + b_dst[1]]);
  }
  asm volatile("s_waitcnt vmcnt(4)" ::: "memory");   // tiles 0,1 landed; 2 in flight
  __builtin_amdgcn_s_barrier();

  const int arow = (wm << 7) + lr;
  const int brow = (wn << 6) + lr;
  const int phys = (quad ^ ((lr >> 1) & 3)) << 3;

  bf16x8 fA[12], fB[12];
  RDFRAG(0, fA)                              // fragments of tile 0

  for (int kk = 0; kk < 72; ++kk) {
    TILE_STEP(2 * kk,     fA, fB)
    TILE_STEP(2 * kk + 1, fB, fA)
  }

  // epilogue: out[b][co][h][w] = acc * d[b][co]
#pragma unroll
  for (int nt = 0; nt < 4; ++nt) {
    const int n = n0 + (wn << 6) + (nt << 4) + lr;
    const float dv = d[(b << 9) + n];
#pragma unroll
    for (int mt = 0; mt < 8; ++mt) {
#pragma unroll
      for (int r = 0; r < 4; ++r) {
        int m = (wm << 7) + (mt << 4) + (quad << 2) + r;   // pixel in tile [0,256)
        int h = h0 + (m >> 6), w = m & 63;
        out[((size_t)((b << 9) + n) << 12) + (h << 6) + w] = acc[mt][nt][r] * dv;
      }
    }
  }
}

extern "C" void kernel_launch(void* const* d_in, const int* in_sizes, int n_in,
                              void* d_out, int out_size, void* d_ws, size_t ws_size,
                              hipStream_t stream) {
  const float* x      = (const float*)d_in[0];   // [16,512,64,64]
  const float* w      = (const float*)d_in[1];   // [16,512]
  const float* weight = (const float*)d_in[2];   // [512,512,3,3]
  const float* aw     = (const float*)d_in[3];   // [512,512]
  const float* ab     = (const float*)d_in[4];   // [512]
  float* out = (float*)d_out;

  char* ws = (char*)d_ws;
  const size_t XP_BYTES  = (size_t)16 * 66 * 66 * 512 * 2;  // 71,368,704
  const size_t WT_BYTES  = (size_t)9 * 512 * 512 * 2;       //  4,718,592
  bf16_t* xp   = (bf16_t*)ws;
  bf16_t* w_t  = (bf16_t*)(ws + XP_BYTES);
  float*  s    = (float*)(ws + XP_BYTES + WT_BYTES);
  float*  wsq  = (float*)(ws + XP_BYTES + WT_BYTES + 32768);
  float*  dbuf = (float*)(ws + XP_BYTES + WT_BYTES + 32768 + 1048576);

  static int attr_done = 0;
  if (!attr_done) {
    hipFuncSetAttribute(reinterpret_cast<const void*>(conv_kernel),
                        hipFuncAttributeMaxDynamicSharedMemorySize, 131072);
    attr_done = 1;
  }

  halo_kernel<<<1040, 256, 0, stream>>>(xp);
  s_kernel<<<512, 256, 0, stream>>>(w, aw, ab, s);
  prep_w_kernel<<<1024, 256, 0, stream>>>(weight, wsq, w_t);
  d_kernel<<<512, 256, 0, stream>>>(wsq, s, dbuf);
  xmod_kernel<<<1024, 256, 0, stream>>>(x, s, xp);
  conv_kernel<<<512, 512, 131072, stream>>>(xp, w_t, dbuf, out);
}